// Round 1
// baseline (1721.844 us; speedup 1.0000x reference)
//
#include <hip/hip_runtime.h>
#include <math.h>

#define BB 32
#define CC 128
#define HH 56
#define WW 56
#define DD 10
#define HWHW 3136          // H*W
#define TOK 100352         // B*H*W
#define BH 1792            // B*H
#define ND 560             // W*d
#define NN 3136            // W*W
#define CE 512             // E*C

// ---------------- LN1: x[B,C,H,W] -> u[B,H,W,C] (channels-last) ----------------
__global__ __launch_bounds__(256) void ln1_kernel(const float* __restrict__ x,
    const float* __restrict__ g, const float* __restrict__ bt,
    float* __restrict__ u) {
  int bh = blockIdx.x;            // b*56 + h
  int b = bh / HH, h = bh % HH;
  __shared__ float lds[WW][CC + 1];
  __shared__ float mu[WW], rs[WW];
  const float* xp = x + ((size_t)b * CC) * HWHW + (size_t)h * WW;
  for (int idx = threadIdx.x; idx < CC * WW; idx += 256) {
    int c = idx / WW, w = idx % WW;
    lds[w][c] = xp[(size_t)c * HWHW + w];
  }
  __syncthreads();
  if (threadIdx.x < WW) {
    int w = threadIdx.x;
    float s = 0.f, ss = 0.f;
    for (int c = 0; c < CC; ++c) { float v = lds[w][c]; s += v; ss += v * v; }
    float m = s * (1.0f / CC);
    float var = ss * (1.0f / CC) - m * m;
    mu[w] = m; rs[w] = rsqrtf(var + 1e-5f);
  }
  __syncthreads();
  float* up = u + (size_t)bh * (WW * CC);
  for (int idx = threadIdx.x; idx < WW * CC; idx += 256) {
    int w = idx >> 7, c = idx & 127;
    up[idx] = (lds[w][c] - mu[w]) * rs[w] * g[c] + bt[c];
  }
}

// ---------------- pd: u -> pd_h [B*H,560], pd_wT [B*W,560] ----------------
__global__ __launch_bounds__(256) void pd_kernel(const float* __restrict__ u,
    const float* __restrict__ hwnd, const float* __restrict__ hbnd,
    const float* __restrict__ wwnd, const float* __restrict__ wbnd,
    float* __restrict__ pdh, float* __restrict__ pdw) {
  int bh = blockIdx.x;            // b*56 + h
  int b = bh / HH, h = bh % HH;
  __shared__ float lds[WW][CC + 1];
  __shared__ float wl[2][CC * DD];
  const float* up = u + (size_t)bh * (WW * CC);
  for (int idx = threadIdx.x; idx < WW * CC; idx += 256)
    lds[idx >> 7][idx & 127] = up[idx];
  for (int idx = threadIdx.x; idx < CC * DD; idx += 256) {
    wl[0][idx] = hwnd[idx];
    wl[1][idx] = wwnd[idx];
  }
  __syncthreads();
  for (int t = threadIdx.x; t < 2 * ND; t += 256) {
    int which = t >= ND;
    int tt = which ? t - ND : t;
    int w = tt / DD, dd = tt % DD;
    const float* wp = wl[which];
    float s = 0.f;
    #pragma unroll 8
    for (int c = 0; c < CC; ++c) s += lds[w][c] * wp[c * DD + dd];
    if (!which) pdh[(size_t)bh * ND + tt] = s + hbnd[dd];
    else        pdw[((size_t)(b * WW + w)) * ND + (size_t)h * DD + dd] = s + wbnd[dd];
  }
}

// ---------------- generic fp32 GEMM: C = A[M,K] @ Bw[K,N] + bias (+ x residual) ----------------
template <bool RESID>
__global__ __launch_bounds__(256) void gemm_kernel(
    const float* __restrict__ A, const float* __restrict__ Bw,
    const float* __restrict__ bias, float* __restrict__ Cout,
    int M, int N, int K, const float* __restrict__ xres) {
  __shared__ float As[64][17];
  __shared__ float Bs[16][65];
  int row0 = blockIdx.y * 64, col0 = blockIdx.x * 64;
  int tx = threadIdx.x & 15, ty = threadIdx.x >> 4;
  float acc[4][4] = {};
  for (int k0 = 0; k0 < K; k0 += 16) {
    for (int idx = threadIdx.x; idx < 64 * 16; idx += 256) {
      int r = idx >> 4, kk = idx & 15;
      As[r][kk] = A[(size_t)(row0 + r) * K + k0 + kk];
    }
    for (int idx = threadIdx.x; idx < 16 * 64; idx += 256) {
      int kk = idx >> 6, n = idx & 63;
      Bs[kk][n] = Bw[(size_t)(k0 + kk) * N + col0 + n];
    }
    __syncthreads();
    #pragma unroll
    for (int kk = 0; kk < 16; ++kk) {
      float a[4], bv[4];
      #pragma unroll
      for (int i = 0; i < 4; ++i) a[i] = As[ty * 4 + i][kk];
      #pragma unroll
      for (int j = 0; j < 4; ++j) bv[j] = Bs[kk][tx * 4 + j];
      #pragma unroll
      for (int i = 0; i < 4; ++i)
        #pragma unroll
        for (int j = 0; j < 4; ++j) acc[i][j] += a[i] * bv[j];
    }
    __syncthreads();
  }
  #pragma unroll
  for (int i = 0; i < 4; ++i) {
    int r = row0 + ty * 4 + i;
    #pragma unroll
    for (int j = 0; j < 4; ++j) {
      int cc = col0 + tx * 4 + j;
      float v = acc[i][j] + bias[cc];
      if (RESID) {
        int b = r / HWHW, pos = r % HWHW;
        v += xres[((size_t)(b * CC + cc)) * HWHW + pos];
      }
      Cout[(size_t)r * N + cc] = v;
    }
  }
}

// ---------------- softmax over contiguous rows of 56 (both buffers) ----------------
__global__ __launch_bounds__(256) void softmax56_kernel(float* __restrict__ ph,
                                                        float* __restrict__ pw) {
  int wave = (blockIdx.x * 256 + threadIdx.x) >> 6;
  int lane = threadIdx.x & 63;
  if (wave >= 2 * TOK) return;
  float* buf = wave < TOK ? ph : pw;
  int row = wave < TOK ? wave : wave - TOK;
  float* p = buf + (size_t)row * WW;
  float xv = lane < WW ? p[lane] : -INFINITY;
  float m = xv;
  for (int o = 32; o > 0; o >>= 1) m = fmaxf(m, __shfl_xor(m, o));
  float e = lane < WW ? __expf(xv - m) : 0.f;
  float s = e;
  for (int o = 32; o > 0; o >>= 1) s += __shfl_xor(s, o);
  if (lane < WW) p[lane] = e / s;
}

// ---------------- mix over W per (b,h) row: acc += p_h @ u_row ----------------
__global__ __launch_bounds__(256) void mix_h_kernel(const float* __restrict__ ph,
    const float* __restrict__ u, float* __restrict__ acc) {
  int bh = blockIdx.x;
  __shared__ float ulds[WW][CC + 1];
  __shared__ float plds[WW][WW + 1];
  const float* up = u + (size_t)bh * (WW * CC);
  for (int idx = threadIdx.x; idx < WW * CC; idx += 256)
    ulds[idx >> 7][idx & 127] = up[idx];
  const float* pp = ph + (size_t)bh * NN;
  for (int idx = threadIdx.x; idx < NN; idx += 256)
    plds[idx / WW][idx % WW] = pp[idx];
  __syncthreads();
  float* ap = acc + (size_t)bh * (WW * CC);
  for (int idx = threadIdx.x; idx < WW * CC; idx += 256) {
    int i = idx >> 7, c = idx & 127;
    float s = 0.f;
    #pragma unroll 8
    for (int j = 0; j < WW; ++j) s += plds[i][j] * ulds[j][c];
    ap[idx] += s;
  }
}

// ---------------- mix over H per (b,w) column: acc += p_w @ u_col ----------------
__global__ __launch_bounds__(256) void mix_w_kernel(const float* __restrict__ pw,
    const float* __restrict__ u, float* __restrict__ acc) {
  int bw = blockIdx.x;            // b*56 + w
  int b = bw / WW, w = bw % WW;
  __shared__ float ulds[HH][CC + 1];
  __shared__ float plds[HH][HH + 1];
  const float* up = u + ((size_t)b * HWHW + w) * CC;
  for (int idx = threadIdx.x; idx < HH * CC; idx += 256) {
    int hh = idx >> 7, c = idx & 127;
    ulds[hh][c] = up[(size_t)hh * (WW * CC) + c];
  }
  const float* pp = pw + (size_t)bw * NN;
  for (int idx = threadIdx.x; idx < NN; idx += 256)
    plds[idx / HH][idx % HH] = pp[idx];
  __syncthreads();
  float* ap = acc + ((size_t)b * HWHW + w) * CC;
  for (int idx = threadIdx.x; idx < HH * CC; idx += 256) {
    int i = idx >> 7, c = idx & 127;
    float s = 0.f;
    #pragma unroll 8
    for (int j = 0; j < HH; ++j) s += plds[i][j] * ulds[j][c];
    ap[(size_t)i * (WW * CC) + c] += s;
  }
}

// ---------------- LN2: per-token (rows of 128 contiguous) ----------------
__global__ __launch_bounds__(256) void ln2_kernel(const float* __restrict__ xt2,
    const float* __restrict__ g, const float* __restrict__ bt,
    float* __restrict__ v) {
  int wave = (blockIdx.x * 256 + threadIdx.x) >> 6;
  int lane = threadIdx.x & 63;
  if (wave >= TOK) return;
  const float* xp = xt2 + (size_t)wave * CC;
  float a = xp[lane], b2 = xp[lane + 64];
  float s = a + b2, ss = a * a + b2 * b2;
  for (int o = 32; o > 0; o >>= 1) { s += __shfl_xor(s, o); ss += __shfl_xor(ss, o); }
  float m = s * (1.0f / CC);
  float var = ss * (1.0f / CC) - m * m;
  float rs = rsqrtf(var + 1e-5f);
  float* vp = v + (size_t)wave * CC;
  vp[lane]      = (a  - m) * rs * g[lane]      + bt[lane];
  vp[lane + 64] = (b2 - m) * rs * g[lane + 64] + bt[lane + 64];
}

// ---------------- fused MLP: out = transpose(xt2 + gelu(v@fc1+b1)@fc2+b2) ----------------
__global__ __launch_bounds__(256) void mlp_kernel(const float* __restrict__ v,
    const float* __restrict__ w1, const float* __restrict__ b1,
    const float* __restrict__ w2, const float* __restrict__ b2,
    const float* __restrict__ xt2, float* __restrict__ out) {
  int tok0 = blockIdx.x * 64;
  __shared__ float vlds[64][CC + 1];
  __shared__ float w1lds[CC][65];
  __shared__ float hlds[64][65];
  __shared__ float w2lds[64][CC + 1];
  float oacc[8][4] = {};
  int txh = threadIdx.x & 15, tyh = threadIdx.x >> 4;   // h-tile: 4 hid x 4 tok
  int txo = threadIdx.x & 31, tyo = threadIdx.x >> 5;   // out: 4 c x 8 tok
  for (int idx = threadIdx.x; idx < 64 * CC; idx += 256)
    vlds[idx >> 7][idx & 127] = v[(size_t)tok0 * CC + idx];
  __syncthreads();
  for (int hc = 0; hc < 8; ++hc) {
    for (int idx = threadIdx.x; idx < CC * 64; idx += 256) {
      int k = idx >> 6, n = idx & 63;
      w1lds[k][n] = w1[(size_t)k * CE + hc * 64 + n];
    }
    __syncthreads();
    float hacc[4][4] = {};
    #pragma unroll 4
    for (int k = 0; k < CC; ++k) {
      float a[4], bb[4];
      #pragma unroll
      for (int i = 0; i < 4; ++i) a[i] = vlds[tyh * 4 + i][k];
      #pragma unroll
      for (int j = 0; j < 4; ++j) bb[j] = w1lds[k][txh * 4 + j];
      #pragma unroll
      for (int i = 0; i < 4; ++i)
        #pragma unroll
        for (int j = 0; j < 4; ++j) hacc[i][j] += a[i] * bb[j];
    }
    __syncthreads();
    #pragma unroll
    for (int i = 0; i < 4; ++i)
      #pragma unroll
      for (int j = 0; j < 4; ++j) {
        float xv = hacc[i][j] + b1[hc * 64 + txh * 4 + j];
        hlds[tyh * 4 + i][txh * 4 + j] = 0.5f * xv * (1.0f + erff(xv * 0.70710678f));
      }
    for (int idx = threadIdx.x; idx < 64 * CC; idx += 256) {
      int k = idx >> 7, c = idx & 127;
      w2lds[k][c] = w2[((size_t)(hc * 64 + k)) * CC + c];
    }
    __syncthreads();
    #pragma unroll 4
    for (int k = 0; k < 64; ++k) {
      float bb[4];
      #pragma unroll
      for (int j = 0; j < 4; ++j) bb[j] = w2lds[k][txo * 4 + j];
      #pragma unroll
      for (int i = 0; i < 8; ++i) {
        float hv = hlds[tyo * 8 + i][k];
        #pragma unroll
        for (int j = 0; j < 4; ++j) oacc[i][j] += hv * bb[j];
      }
    }
    __syncthreads();
  }
  // epilogue: + b2 + xt2 residual, stage transposed write through vlds
  #pragma unroll
  for (int i = 0; i < 8; ++i) {
    int t = tyo * 8 + i;
    const float* xp = xt2 + (size_t)(tok0 + t) * CC;
    #pragma unroll
    for (int j = 0; j < 4; ++j) {
      int c = txo * 4 + j;
      vlds[t][c] = oacc[i][j] + b2[c] + xp[c];
    }
  }
  __syncthreads();
  int b = tok0 / HWHW;
  int pos0 = tok0 % HWHW;
  for (int idx = threadIdx.x; idx < 64 * CC; idx += 256) {
    int c = idx >> 6, t = idx & 63;
    out[((size_t)(b * CC + c)) * HWHW + pos0 + t] = vlds[t][c];
  }
}

extern "C" void kernel_launch(void* const* d_in, const int* in_sizes, int n_in,
                              void* d_out, int out_size, void* d_ws, size_t ws_size,
                              hipStream_t stream) {
  const float* x     = (const float*)d_in[0];
  const float* ln1_g = (const float*)d_in[1];
  const float* ln1_b = (const float*)d_in[2];
  const float* h_wnd = (const float*)d_in[3];
  const float* h_bnd = (const float*)d_in[4];
  const float* h_wnn = (const float*)d_in[5];
  const float* h_bnn = (const float*)d_in[6];
  const float* w_wnd = (const float*)d_in[7];
  const float* w_bnd = (const float*)d_in[8];
  const float* w_wnn = (const float*)d_in[9];
  const float* w_bnn = (const float*)d_in[10];
  const float* pc_w  = (const float*)d_in[11];
  const float* pc_b  = (const float*)d_in[12];
  const float* po_w  = (const float*)d_in[13];
  const float* po_b  = (const float*)d_in[14];
  const float* ln2_g = (const float*)d_in[15];
  const float* ln2_b = (const float*)d_in[16];
  const float* fc1_w = (const float*)d_in[17];
  const float* fc1_b = (const float*)d_in[18];
  const float* fc2_w = (const float*)d_in[19];
  const float* fc2_b = (const float*)d_in[20];
  float* out = (float*)d_out;

  // workspace layout (floats): u | acc | scratch(pd_h|pd_wT|ph|pw, reused as xt2)
  float* u   = (float*)d_ws;                  // 12,845,056
  float* acc = u + (size_t)TOK * CC;          // 12,845,056
  float* scr = acc + (size_t)TOK * CC;        // 13,246,464 region
  float* pdh = scr;                           //  1,003,520
  float* pdw = pdh + (size_t)BH * ND;         //  1,003,520
  float* ph  = pdw + (size_t)BH * ND;         //  5,619,712
  float* pw  = ph + (size_t)BH * NN;          //  5,619,712
  float* xt2 = scr;                           // reuse (pd/ph/pw dead by then)
  float* v   = u;                             // reuse (u dead by then)

  ln1_kernel<<<BH, 256, 0, stream>>>(x, ln1_g, ln1_b, u);
  pd_kernel<<<BH, 256, 0, stream>>>(u, h_wnd, h_bnd, w_wnd, w_bnd, pdh, pdw);
  gemm_kernel<false><<<dim3(NN / 64, BH / 64), 256, 0, stream>>>(
      pdh, h_wnn, h_bnn, ph, BH, NN, ND, nullptr);
  gemm_kernel<false><<<dim3(NN / 64, BH / 64), 256, 0, stream>>>(
      pdw, w_wnn, w_bnn, pw, BH, NN, ND, nullptr);
  softmax56_kernel<<<(2 * TOK) / 4, 256, 0, stream>>>(ph, pw);
  gemm_kernel<false><<<dim3(CC / 64, TOK / 64), 256, 0, stream>>>(
      u, pc_w, pc_b, acc, TOK, CC, CC, nullptr);
  mix_h_kernel<<<BH, 256, 0, stream>>>(ph, u, acc);
  mix_w_kernel<<<BB * WW, 256, 0, stream>>>(pw, u, acc);
  gemm_kernel<true><<<dim3(CC / 64, TOK / 64), 256, 0, stream>>>(
      acc, po_w, po_b, xt2, TOK, CC, CC, x);
  ln2_kernel<<<TOK / 4, 256, 0, stream>>>(xt2, ln2_g, ln2_b, v);
  mlp_kernel<<<TOK / 64, 256, 0, stream>>>(v, fc1_w, fc1_b, fc2_w, fc2_b, xt2, out);
}

// Round 2
// 397.562 us; speedup vs baseline: 4.3310x; 4.3310x over previous
//
#include <hip/hip_runtime.h>
#include <math.h>

#define BB 32
#define CC 128
#define HH 56
#define WW 56
#define HWHW 3136
#define TOK 100352         // B*H*W
#define BH 1792            // B*H
#define NDP 576            // padded W*d (560 -> 576)
#define NNP 3200           // padded W*W (3136 -> 3200)

typedef __attribute__((ext_vector_type(8))) short bhalf8;
typedef __attribute__((ext_vector_type(4))) float f32x4;
typedef __attribute__((ext_vector_type(4))) unsigned int u32x4;

__device__ inline unsigned short f2bf(float f) {
  unsigned int x = __float_as_uint(f);
  unsigned int r = (x + 0x7FFFu + ((x >> 16) & 1u)) >> 16;
  return (unsigned short)r;
}
__device__ inline unsigned int pack2(float a, float b) {
  return (unsigned int)f2bf(a) | ((unsigned int)f2bf(b) << 16);
}
__device__ inline f32x4 MFMA(bhalf8 a, bhalf8 b, f32x4 c) {
  return __builtin_amdgcn_mfma_f32_16x16x32_bf16(a, b, c, 0, 0, 0);
}
// swizzled LDS frag read: tile [rows][CH*8] bf16, chunk XOR (row&7)
template <int CH>
__device__ inline bhalf8 ldsFrag(const unsigned short* base, int row, int chunk) {
  return *reinterpret_cast<const bhalf8*>(base + row * (CH * 8) + ((chunk ^ (row & 7)) * 8));
}
__device__ inline float gelu_f(float x) {
  float x3 = x * x * x;
  float z = 0.7978845608028654f * (x + 0.044715f * x3);
  float e = __expf(2.0f * z);
  float t = 1.0f - 2.0f / (e + 1.0f);
  return 0.5f * x * (1.0f + t);
}

// ---------------- weight convert/transpose to bf16 + zero pdh/pdw pads ----------------
__global__ __launch_bounds__(256) void wcvt_kernel(
    const float* __restrict__ hwnn, const float* __restrict__ wwnn,
    const float* __restrict__ pcw, const float* __restrict__ pow_,
    const float* __restrict__ fc1w, const float* __restrict__ fc2w,
    const float* __restrict__ hwnd, const float* __restrict__ wwnd,
    unsigned short* __restrict__ wnnTh, unsigned short* __restrict__ wnnTw,
    unsigned short* __restrict__ pcT, unsigned short* __restrict__ poT,
    unsigned short* __restrict__ fc1T, unsigned short* __restrict__ fc2T,
    unsigned short* __restrict__ wcatT, u32x4* __restrict__ pdzero) {
  int gt = blockIdx.x * 256 + threadIdx.x;
  int gs = gridDim.x * 256;
  for (int i = gt; i < 258048; i += gs) { u32x4 z = {0, 0, 0, 0}; pdzero[i] = z; }
  for (int i = gt; i < 3200 * 576; i += gs) {
    int k = i / 3200, n = i % 3200;
    float v = (n < 3136 && k < 560) ? hwnn[(size_t)k * 3136 + n] : 0.f;
    wnnTh[(size_t)n * 576 + k] = f2bf(v);
  }
  for (int i = gt; i < 3200 * 576; i += gs) {
    int k = i / 3200, n = i % 3200;
    float v = (n < 3136 && k < 560) ? wwnn[(size_t)k * 3136 + n] : 0.f;
    wnnTw[(size_t)n * 576 + k] = f2bf(v);
  }
  for (int i = gt; i < 128 * 128; i += gs) { int k = i >> 7, n = i & 127; pcT[n * 128 + k] = f2bf(pcw[i]); }
  for (int i = gt; i < 128 * 128; i += gs) { int k = i >> 7, n = i & 127; poT[n * 128 + k] = f2bf(pow_[i]); }
  for (int i = gt; i < 128 * 512; i += gs) { int k = i >> 9, n = i & 511; fc1T[n * 128 + k] = f2bf(fc1w[i]); }
  for (int i = gt; i < 512 * 128; i += gs) { int k = i >> 7, n = i & 127; fc2T[n * 512 + k] = f2bf(fc2w[i]); }
  for (int i = gt; i < 128 * 32; i += gs) {
    int k = i >> 5, n = i & 31;
    float v = n < 10 ? hwnd[k * 10 + n] : (n < 20 ? wwnd[k * 10 + (n - 10)] : 0.f);
    wcatT[n * 128 + k] = f2bf(v);
  }
}

// ---------------- LN1: x[B,C,H,W] -> ubf[B,H,W,C] bf16 ----------------
__global__ __launch_bounds__(256) void ln1_kernel(const float* __restrict__ x,
    const float* __restrict__ g, const float* __restrict__ bt,
    unsigned short* __restrict__ ubf) {
  int bh = blockIdx.x;
  int b = bh / HH, h = bh % HH;
  __shared__ float lds[WW][CC + 1];
  __shared__ float mu[WW], rs[WW];
  const float* xp = x + ((size_t)b * CC) * HWHW + (size_t)h * WW;
  for (int idx = threadIdx.x; idx < CC * WW; idx += 256) {
    int c = idx / WW, w = idx % WW;
    lds[w][c] = xp[(size_t)c * HWHW + w];
  }
  __syncthreads();
  if (threadIdx.x < WW) {
    int w = threadIdx.x;
    float s = 0.f, ss = 0.f;
    for (int c = 0; c < CC; ++c) { float v = lds[w][c]; s += v; ss += v * v; }
    float m = s * (1.0f / CC);
    float var = ss * (1.0f / CC) - m * m;
    mu[w] = m; rs[w] = rsqrtf(var + 1e-5f);
  }
  __syncthreads();
  unsigned short* up = ubf + (size_t)bh * (WW * CC);
  for (int idx = threadIdx.x; idx < WW * CC; idx += 256) {
    int w = idx >> 7, c = idx & 127;
    up[idx] = f2bf((lds[w][c] - mu[w]) * rs[w] * g[c] + bt[c]);
  }
}

// ---------------- pd (MFMA): per-token 128->20 projection, scatter to pdh/pdw ----------------
__global__ __launch_bounds__(256) void pd_mfma(const unsigned short* __restrict__ ubf,
    const unsigned short* __restrict__ wcatT, const float* __restrict__ hbnd,
    const float* __restrict__ wbnd, unsigned short* __restrict__ pdh,
    unsigned short* __restrict__ pdw) {
  __shared__ __align__(16) unsigned short sU[64 * 128];
  __shared__ __align__(16) unsigned short sW[32 * 128];
  int tid = threadIdx.x;
  int tok0 = blockIdx.x * 64;
  #pragma unroll
  for (int i = 0; i < 4; ++i) {
    int s = i * 256 + tid; int r = s >> 4, c = s & 15;
    u32x4 v = *reinterpret_cast<const u32x4*>(ubf + (size_t)(tok0 + r) * 128 + c * 8);
    *reinterpret_cast<u32x4*>(sU + r * 128 + ((c ^ (r & 7)) * 8)) = v;
  }
  #pragma unroll
  for (int i = 0; i < 2; ++i) {
    int s = i * 256 + tid; int r = s >> 4, c = s & 15;
    u32x4 v = *reinterpret_cast<const u32x4*>(wcatT + (size_t)r * 128 + c * 8);
    *reinterpret_cast<u32x4*>(sW + r * 128 + ((c ^ (r & 7)) * 8)) = v;
  }
  __syncthreads();
  int wid = tid >> 6, lane = tid & 63, l16 = lane & 15, lk = lane >> 4;
  f32x4 acc[2] = {};
  #pragma unroll
  for (int kk = 0; kk < 4; ++kk) {
    bhalf8 a = ldsFrag<16>(sU, wid * 16 + l16, kk * 4 + lk);
    #pragma unroll
    for (int f = 0; f < 2; ++f) {
      bhalf8 b = ldsFrag<16>(sW, f * 16 + l16, kk * 4 + lk);
      acc[f] = MFMA(a, b, acc[f]);
    }
  }
  #pragma unroll
  for (int f = 0; f < 2; ++f) {
    int n = f * 16 + l16;
    #pragma unroll
    for (int r = 0; r < 4; ++r) {
      int tok = tok0 + wid * 16 + lk * 4 + r;
      float v = acc[f][r];
      if (n < 10) {
        pdh[((size_t)(tok / 56)) * NDP + (size_t)(tok % 56) * 10 + n] = f2bf(v + hbnd[n]);
      } else if (n < 20) {
        int b = tok / HWHW; int rem = tok % HWHW; int hh = rem / 56; int w = rem % 56;
        pdw[((size_t)(b * 56 + w)) * NDP + (size_t)hh * 10 + (n - 10)] = f2bf(v + wbnd[n - 10]);
      }
    }
  }
}

// ---------------- generic 128x128 bf16 MFMA GEMM ----------------
// EPI: 0 = bias, f32 store;  1 = bias + transposed-x residual, f32 store
template <int EPI, bool ABF16>
__global__ __launch_bounds__(256) void gemm128(
    const void* __restrict__ Ap, const unsigned short* __restrict__ BT,
    const float* __restrict__ bias, float* __restrict__ Cout,
    int K, int lda, int ldc, int Nv, const float* __restrict__ xres) {
  __shared__ __align__(16) unsigned short sA[128 * 64];
  __shared__ __align__(16) unsigned short sB[128 * 64];
  int tid = threadIdx.x;
  int row0 = blockIdx.y * 128, col0 = blockIdx.x * 128;
  int wid = tid >> 6, lane = tid & 63;
  int wm = wid >> 1, wn = wid & 1;
  int l16 = lane & 15, lk = lane >> 4;
  f32x4 acc[4][4] = {};
  for (int k0 = 0; k0 < K; k0 += 64) {
    if (ABF16) {
      const unsigned short* A = (const unsigned short*)Ap;
      #pragma unroll
      for (int i = 0; i < 4; ++i) {
        int s = i * 256 + tid; int r = s >> 3, c = s & 7;
        u32x4 v = *reinterpret_cast<const u32x4*>(A + (size_t)(row0 + r) * lda + k0 + c * 8);
        *reinterpret_cast<u32x4*>(sA + r * 64 + ((c ^ (r & 7)) * 8)) = v;
      }
    } else {
      const float* A = (const float*)Ap;
      #pragma unroll
      for (int i = 0; i < 4; ++i) {
        int s = i * 256 + tid; int r = s >> 3, c = s & 7;
        const float* p = A + (size_t)(row0 + r) * lda + k0 + c * 8;
        float4 lo = *reinterpret_cast<const float4*>(p);
        float4 hi = *reinterpret_cast<const float4*>(p + 4);
        u32x4 v = { pack2(lo.x, lo.y), pack2(lo.z, lo.w), pack2(hi.x, hi.y), pack2(hi.z, hi.w) };
        *reinterpret_cast<u32x4*>(sA + r * 64 + ((c ^ (r & 7)) * 8)) = v;
      }
    }
    #pragma unroll
    for (int i = 0; i < 4; ++i) {
      int s = i * 256 + tid; int r = s >> 3, c = s & 7;
      u32x4 v = *reinterpret_cast<const u32x4*>(BT + (size_t)(col0 + r) * K + k0 + c * 8);
      *reinterpret_cast<u32x4*>(sB + r * 64 + ((c ^ (r & 7)) * 8)) = v;
    }
    __syncthreads();
    bhalf8 af[4][2], bf[4][2];
    #pragma unroll
    for (int f = 0; f < 4; ++f)
      #pragma unroll
      for (int kk = 0; kk < 2; ++kk) {
        af[f][kk] = ldsFrag<8>(sA, wm * 64 + f * 16 + l16, kk * 4 + lk);
        bf[f][kk] = ldsFrag<8>(sB, wn * 64 + f * 16 + l16, kk * 4 + lk);
      }
    #pragma unroll
    for (int i = 0; i < 4; ++i)
      #pragma unroll
      for (int j = 0; j < 4; ++j) {
        acc[i][j] = MFMA(af[i][0], bf[j][0], acc[i][j]);
        acc[i][j] = MFMA(af[i][1], bf[j][1], acc[i][j]);
      }
    __syncthreads();
  }
  #pragma unroll
  for (int i = 0; i < 4; ++i) {
    int rbase = row0 + wm * 64 + i * 16 + lk * 4;
    #pragma unroll
    for (int j = 0; j < 4; ++j) {
      int col = col0 + wn * 64 + j * 16 + l16;
      if (col < Nv) {
        float bv = bias[col];
        #pragma unroll
        for (int r = 0; r < 4; ++r) {
          int row = rbase + r;
          float v = acc[i][j][r] + bv;
          if (EPI == 1) {
            int b = row / HWHW, pos = row % HWHW;
            v += xres[((size_t)(b * CC + col)) * HWHW + pos];
          }
          Cout[(size_t)row * ldc + col] = v;
        }
      }
    }
  }
}

// ---------------- softmax over contiguous groups of 56 (padded row stride 3200) ----------------
__global__ __launch_bounds__(256) void softmax56_kernel(float* __restrict__ ph,
                                                        float* __restrict__ pw) {
  int wave = (blockIdx.x * 256 + threadIdx.x) >> 6;
  int lane = threadIdx.x & 63;
  if (wave >= 2 * TOK) return;
  float* buf = wave < TOK ? ph : pw;
  int row = wave < TOK ? wave : wave - TOK;
  int bh = row / 56, i = row % 56;
  float* p = buf + (size_t)bh * NNP + (size_t)i * 56;
  float xv = lane < WW ? p[lane] : -INFINITY;
  float m = xv;
  for (int o = 32; o > 0; o >>= 1) m = fmaxf(m, __shfl_xor(m, o));
  float e = lane < WW ? __expf(xv - m) : 0.f;
  float s = e;
  for (int o = 32; o > 0; o >>= 1) s += __shfl_xor(s, o);
  if (lane < WW) p[lane] = e / s;
}

// ---------------- mixes (MFMA, 56 padded to 64): accm += P(56x56) @ U(56x128) ----------------
template <bool WDIR>
__global__ __launch_bounds__(256) void mix_mfma(const float* __restrict__ P,
    const unsigned short* __restrict__ ubf, float* __restrict__ accm) {
  int blk = blockIdx.x;
  int b = blk / 56, rc = blk % 56;
  __shared__ __align__(16) unsigned short sP[64 * 64];
  __shared__ __align__(16) unsigned short sU[128 * 64];
  int tid = threadIdx.x;
  const float* prow = P + (size_t)blk * NNP;
  for (int s = tid; s < 512; s += 256) {
    int r = s >> 3, c = s & 7;
    unsigned int w[4];
    #pragma unroll
    for (int e = 0; e < 8; e += 2) {
      int j0 = c * 8 + e;
      float f0 = (r < 56 && j0 < 56) ? prow[r * 56 + j0] : 0.f;
      float f1 = (r < 56 && j0 + 1 < 56) ? prow[r * 56 + j0 + 1] : 0.f;
      w[e >> 1] = pack2(f0, f1);
    }
    u32x4 v = {w[0], w[1], w[2], w[3]};
    *reinterpret_cast<u32x4*>(sP + r * 64 + ((c ^ (r & 7)) * 8)) = v;
  }
  for (int s = tid; s < 1024; s += 256) {
    int j = s >> 4, cc = s & 15;
    unsigned short e8[8];
    if (j < 56) {
      size_t tok = WDIR ? ((size_t)b * HWHW + (size_t)j * 56 + rc)
                        : ((size_t)blk * 56 + j);
      *reinterpret_cast<u32x4*>(e8) = *reinterpret_cast<const u32x4*>(ubf + tok * 128 + cc * 8);
    } else {
      #pragma unroll
      for (int e = 0; e < 8; ++e) e8[e] = 0;
    }
    #pragma unroll
    for (int e = 0; e < 8; ++e) {
      int cf = cc * 8 + e;
      sU[cf * 64 + (((j >> 3) ^ (cf & 7)) * 8) + (j & 7)] = e8[e];
    }
  }
  __syncthreads();
  int wid = tid >> 6, lane = tid & 63, l16 = lane & 15, lk = lane >> 4;
  f32x4 acc[4][2] = {};
  bhalf8 pa[4][2], ub[2][2];
  #pragma unroll
  for (int f = 0; f < 4; ++f)
    #pragma unroll
    for (int kk = 0; kk < 2; ++kk)
      pa[f][kk] = ldsFrag<8>(sP, f * 16 + l16, kk * 4 + lk);
  #pragma unroll
  for (int f = 0; f < 2; ++f)
    #pragma unroll
    for (int kk = 0; kk < 2; ++kk)
      ub[f][kk] = ldsFrag<8>(sU, wid * 32 + f * 16 + l16, kk * 4 + lk);
  #pragma unroll
  for (int i = 0; i < 4; ++i)
    #pragma unroll
    for (int j = 0; j < 2; ++j) {
      acc[i][j] = MFMA(pa[i][0], ub[j][0], acc[i][j]);
      acc[i][j] = MFMA(pa[i][1], ub[j][1], acc[i][j]);
    }
  #pragma unroll
  for (int i = 0; i < 4; ++i) {
    int irow = i * 16 + lk * 4;
    #pragma unroll
    for (int j = 0; j < 2; ++j) {
      int c = wid * 32 + j * 16 + l16;
      #pragma unroll
      for (int r = 0; r < 4; ++r) {
        int ii = irow + r;
        if (ii < 56) {
          size_t tok = WDIR ? ((size_t)b * HWHW + (size_t)ii * 56 + rc)
                            : ((size_t)blk * 56 + ii);
          accm[tok * 128 + c] += acc[i][j][r];
        }
      }
    }
  }
}

// ---------------- LN2: xt2 fp32 -> vbf bf16 ----------------
__global__ __launch_bounds__(256) void ln2_kernel(const float* __restrict__ xt2,
    const float* __restrict__ g, const float* __restrict__ bt,
    unsigned short* __restrict__ vbf) {
  int wave = (blockIdx.x * 256 + threadIdx.x) >> 6;
  int lane = threadIdx.x & 63;
  if (wave >= TOK) return;
  const float* xp = xt2 + (size_t)wave * CC;
  float a = xp[lane], b2 = xp[lane + 64];
  float s = a + b2, ss = a * a + b2 * b2;
  for (int o = 32; o > 0; o >>= 1) { s += __shfl_xor(s, o); ss += __shfl_xor(ss, o); }
  float m = s * (1.0f / CC);
  float var = ss * (1.0f / CC) - m * m;
  float rs = rsqrtf(var + 1e-5f);
  unsigned short* vp = vbf + (size_t)wave * CC;
  vp[lane]      = f2bf((a  - m) * rs * g[lane]      + bt[lane]);
  vp[lane + 64] = f2bf((b2 - m) * rs * g[lane + 64] + bt[lane + 64]);
}

// ---------------- fused MLP (MFMA): out = T(xt2 + gelu(v@fc1+b1)@fc2+b2) ----------------
__global__ __launch_bounds__(512) void mlp_mfma(const unsigned short* __restrict__ vbf,
    const unsigned short* __restrict__ w1T, const float* __restrict__ b1,
    const unsigned short* __restrict__ w2T, const float* __restrict__ b2,
    const float* __restrict__ xt2, float* __restrict__ out) {
  __shared__ __align__(16) unsigned short sV[128 * 128];
  __shared__ __align__(16) unsigned short sW[128 * 128];
  __shared__ __align__(16) unsigned short sH[128 * 128];
  int tid = threadIdx.x;
  int tok0 = blockIdx.x * 128;
  int wid = tid >> 6, lane = tid & 63, l16 = lane & 15, lk = lane >> 4;
  int wm = wid >> 2, wn = wid & 3;
  #pragma unroll
  for (int i = 0; i < 4; ++i) {
    int s = i * 512 + tid; int r = s >> 4, c = s & 15;
    u32x4 v = *reinterpret_cast<const u32x4*>(vbf + (size_t)(tok0 + r) * 128 + c * 8);
    *reinterpret_cast<u32x4*>(sV + r * 128 + ((c ^ (r & 7)) * 8)) = v;
  }
  f32x4 acc2[4][2] = {};
  for (int hc = 0; hc < 4; ++hc) {
    #pragma unroll
    for (int i = 0; i < 4; ++i) {
      int s = i * 512 + tid; int r = s >> 4, c = s & 15;
      u32x4 v = *reinterpret_cast<const u32x4*>(w1T + (size_t)(hc * 128 + r) * 128 + c * 8);
      *reinterpret_cast<u32x4*>(sW + r * 128 + ((c ^ (r & 7)) * 8)) = v;
    }
    __syncthreads();
    f32x4 acc1[4][2] = {};
    #pragma unroll
    for (int kk = 0; kk < 4; ++kk) {
      bhalf8 av[4], bw[2];
      #pragma unroll
      for (int f = 0; f < 4; ++f) av[f] = ldsFrag<16>(sV, wm * 64 + f * 16 + l16, kk * 4 + lk);
      #pragma unroll
      for (int f = 0; f < 2; ++f) bw[f] = ldsFrag<16>(sW, wn * 32 + f * 16 + l16, kk * 4 + lk);
      #pragma unroll
      for (int i = 0; i < 4; ++i)
        #pragma unroll
        for (int j = 0; j < 2; ++j)
          acc1[i][j] = MFMA(av[i], bw[j], acc1[i][j]);
    }
    __syncthreads();
    float b1v[2];
    #pragma unroll
    for (int j = 0; j < 2; ++j) b1v[j] = b1[hc * 128 + wn * 32 + j * 16 + l16];
    #pragma unroll
    for (int i = 0; i < 4; ++i)
      #pragma unroll
      for (int j = 0; j < 2; ++j) {
        int hl = wn * 32 + j * 16 + l16;
        #pragma unroll
        for (int r = 0; r < 4; ++r) {
          int tokL = wm * 64 + i * 16 + lk * 4 + r;
          float g = gelu_f(acc1[i][j][r] + b1v[j]);
          sH[tokL * 128 + (((hl >> 3) ^ (tokL & 7)) * 8) + (hl & 7)] = f2bf(g);
        }
      }
    #pragma unroll
    for (int i = 0; i < 4; ++i) {
      int s = i * 512 + tid; int r = s >> 4, c = s & 15;
      u32x4 v = *reinterpret_cast<const u32x4*>(w2T + (size_t)r * 512 + hc * 128 + c * 8);
      *reinterpret_cast<u32x4*>(sW + r * 128 + ((c ^ (r & 7)) * 8)) = v;
    }
    __syncthreads();
    #pragma unroll
    for (int kk = 0; kk < 4; ++kk) {
      bhalf8 aw[4], bh[2];
      #pragma unroll
      for (int f = 0; f < 4; ++f) aw[f] = ldsFrag<16>(sW, wm * 64 + f * 16 + l16, kk * 4 + lk);
      #pragma unroll
      for (int f = 0; f < 2; ++f) bh[f] = ldsFrag<16>(sH, wn * 32 + f * 16 + l16, kk * 4 + lk);
      #pragma unroll
      for (int i = 0; i < 4; ++i)
        #pragma unroll
        for (int j = 0; j < 2; ++j)
          acc2[i][j] = MFMA(aw[i], bh[j], acc2[i][j]);
    }
    __syncthreads();
  }
  #pragma unroll
  for (int i = 0; i < 4; ++i) {
    #pragma unroll
    for (int j = 0; j < 2; ++j) {
      #pragma unroll
      for (int r = 0; r < 4; ++r) {
        int c = wm * 64 + i * 16 + lk * 4 + r;
        int tok = tok0 + wn * 32 + j * 16 + l16;
        int b = tok / HWHW, pos = tok % HWHW;
        float v = acc2[i][j][r] + b2[c] + xt2[(size_t)tok * CC + c];
        out[((size_t)(b * CC + c)) * HWHW + pos] = v;
      }
    }
  }
}

extern "C" void kernel_launch(void* const* d_in, const int* in_sizes, int n_in,
                              void* d_out, int out_size, void* d_ws, size_t ws_size,
                              hipStream_t stream) {
  const float* x     = (const float*)d_in[0];
  const float* ln1_g = (const float*)d_in[1];
  const float* ln1_b = (const float*)d_in[2];
  const float* h_wnd = (const float*)d_in[3];
  const float* h_bnd = (const float*)d_in[4];
  const float* h_wnn = (const float*)d_in[5];
  const float* h_bnn = (const float*)d_in[6];
  const float* w_wnd = (const float*)d_in[7];
  const float* w_bnd = (const float*)d_in[8];
  const float* w_wnn = (const float*)d_in[9];
  const float* w_bnn = (const float*)d_in[10];
  const float* pc_w  = (const float*)d_in[11];
  const float* pc_b  = (const float*)d_in[12];
  const float* po_w  = (const float*)d_in[13];
  const float* po_b  = (const float*)d_in[14];
  const float* ln2_g = (const float*)d_in[15];
  const float* ln2_b = (const float*)d_in[16];
  const float* fc1_w = (const float*)d_in[17];
  const float* fc1_b = (const float*)d_in[18];
  const float* fc2_w = (const float*)d_in[19];
  const float* fc2_b = (const float*)d_in[20];
  float* out = (float*)d_out;
  char* ws = (char*)d_ws;

  // ---- workspace layout (bytes) ----
  unsigned short* ubf  = (unsigned short*)(ws + 0);           // 25,690,112  (live ln1..mixes)
  unsigned short* pdh  = (unsigned short*)(ws + 25690112);    //  2,064,384
  unsigned short* pdw  = (unsigned short*)(ws + 27754496);    //  2,064,384
  float* ph            = (float*)(ws + 29818880);             // 22,937,600
  float* pw            = (float*)(ws + 52756480);             // 22,937,600
  float* accm          = (float*)(ws + 75694080);             // 51,380,224
  float* xt2           = (float*)(ws + 0);                    // 51,380,224 (overlays ubf..ph-head; live po..mlp)
  unsigned short* vbf  = (unsigned short*)(ws + 51380224);    // 25,690,112 (overlays pw/accm-head; live ln2..mlp)
  char* wt             = ws + 127074304;
  unsigned short* wnnTh = (unsigned short*)(wt);              // 3,686,400
  unsigned short* wnnTw = (unsigned short*)(wt + 3686400);    // 3,686,400
  unsigned short* pcT   = (unsigned short*)(wt + 7372800);    // 32,768
  unsigned short* poT   = (unsigned short*)(wt + 7405568);    // 32,768
  unsigned short* fc1T  = (unsigned short*)(wt + 7438336);    // 131,072
  unsigned short* fc2T  = (unsigned short*)(wt + 7569408);    // 131,072
  unsigned short* wcatT = (unsigned short*)(wt + 7700480);    // 8,192   (total end 134,782,976)

  wcvt_kernel<<<2048, 256, 0, stream>>>(h_wnn, w_wnn, pc_w, po_w, fc1_w, fc2_w,
      h_wnd, w_wnd, wnnTh, wnnTw, pcT, poT, fc1T, fc2T, wcatT, (u32x4*)pdh);
  ln1_kernel<<<BH, 256, 0, stream>>>(x, ln1_g, ln1_b, ubf);
  pd_mfma<<<TOK / 64, 256, 0, stream>>>(ubf, wcatT, h_bnd, w_bnd, pdh, pdw);
  gemm128<0, true><<<dim3(NNP / 128, BH / 128), 256, 0, stream>>>(
      pdh, wnnTh, h_bnn, ph, NDP, NDP, NNP, HWHW, nullptr);
  gemm128<0, true><<<dim3(NNP / 128, BH / 128), 256, 0, stream>>>(
      pdw, wnnTw, w_bnn, pw, NDP, NDP, NNP, HWHW, nullptr);
  softmax56_kernel<<<(2 * TOK) / 4, 256, 0, stream>>>(ph, pw);
  gemm128<0, true><<<dim3(1, TOK / 128), 256, 0, stream>>>(
      ubf, pcT, pc_b, accm, CC, CC, CC, CC, nullptr);
  mix_mfma<false><<<BH, 256, 0, stream>>>(ph, ubf, accm);
  mix_mfma<true><<<BB * WW, 256, 0, stream>>>(pw, ubf, accm);
  gemm128<1, false><<<dim3(1, TOK / 128), 256, 0, stream>>>(
      accm, poT, po_b, xt2, CC, CC, CC, CC, x);
  ln2_kernel<<<TOK / 4, 256, 0, stream>>>(xt2, ln2_g, ln2_b, vbf);
  mlp_mfma<<<TOK / 128, 512, 0, stream>>>(vbf, fc1T, fc1_b, fc2T, fc2_b, xt2, out);
}

// Round 4
// 332.356 us; speedup vs baseline: 5.1807x; 1.1962x over previous
//
#include <hip/hip_runtime.h>
#include <math.h>

#define BB 32
#define CC 128
#define HH 56
#define WW 56
#define HWHW 3136
#define TOK 100352         // B*H*W
#define BH 1792            // B*H
#define NDP 576            // padded W*d (560 -> 576)
#define NNP 3200           // padded W*W (3136 -> 3200)

typedef __attribute__((ext_vector_type(8))) short bhalf8;
typedef __attribute__((ext_vector_type(4))) float f32x4;
typedef __attribute__((ext_vector_type(4))) unsigned int u32x4;

__device__ inline unsigned short f2bf(float f) {
  unsigned int x = __float_as_uint(f);
  unsigned int r = (x + 0x7FFFu + ((x >> 16) & 1u)) >> 16;
  return (unsigned short)r;
}
__device__ inline float bf2f(unsigned short u) {
  return __uint_as_float(((unsigned int)u) << 16);
}
__device__ inline unsigned int pack2(float a, float b) {
  return (unsigned int)f2bf(a) | ((unsigned int)f2bf(b) << 16);
}
__device__ inline f32x4 MFMA(bhalf8 a, bhalf8 b, f32x4 c) {
  return __builtin_amdgcn_mfma_f32_16x16x32_bf16(a, b, c, 0, 0, 0);
}
// swizzled LDS frag read: tile [rows][CH*8] bf16, chunk XOR (row&7)
template <int CH>
__device__ inline bhalf8 ldsFrag(const unsigned short* base, int row, int chunk) {
  return *reinterpret_cast<const bhalf8*>(base + row * (CH * 8) + ((chunk ^ (row & 7)) * 8));
}
__device__ inline float gelu_f(float x) {
  float x3 = x * x * x;
  float z = 0.7978845608028654f * (x + 0.044715f * x3);
  float e = __expf(2.0f * z);
  float t = 1.0f - 2.0f / (e + 1.0f);
  return 0.5f * x * (1.0f + t);
}

// ---------------- weight convert/transpose to bf16 + zero pdh/pdw pads ----------------
__global__ __launch_bounds__(256) void wcvt_kernel(
    const float* __restrict__ hwnn, const float* __restrict__ wwnn,
    const float* __restrict__ pcw, const float* __restrict__ pow_,
    const float* __restrict__ fc1w, const float* __restrict__ fc2w,
    const float* __restrict__ hwnd, const float* __restrict__ wwnd,
    unsigned short* __restrict__ wnnTh, unsigned short* __restrict__ wnnTw,
    unsigned short* __restrict__ pcT, unsigned short* __restrict__ poT,
    unsigned short* __restrict__ fc1T, unsigned short* __restrict__ fc2T,
    unsigned short* __restrict__ wcatT, u32x4* __restrict__ pdzero) {
  int gt = blockIdx.x * 256 + threadIdx.x;
  int gs = gridDim.x * 256;
  for (int i = gt; i < 258048; i += gs) { u32x4 z = {0, 0, 0, 0}; pdzero[i] = z; }
  for (int i = gt; i < 3200 * 576; i += gs) {
    int k = i / 3200, n = i % 3200;
    float v = (n < 3136 && k < 560) ? hwnn[(size_t)k * 3136 + n] : 0.f;
    wnnTh[(size_t)n * 576 + k] = f2bf(v);
  }
  for (int i = gt; i < 3200 * 576; i += gs) {
    int k = i / 3200, n = i % 3200;
    float v = (n < 3136 && k < 560) ? wwnn[(size_t)k * 3136 + n] : 0.f;
    wnnTw[(size_t)n * 576 + k] = f2bf(v);
  }
  for (int i = gt; i < 128 * 128; i += gs) { int k = i >> 7, n = i & 127; pcT[n * 128 + k] = f2bf(pcw[i]); }
  for (int i = gt; i < 128 * 128; i += gs) { int k = i >> 7, n = i & 127; poT[n * 128 + k] = f2bf(pow_[i]); }
  for (int i = gt; i < 128 * 512; i += gs) { int k = i >> 9, n = i & 511; fc1T[n * 128 + k] = f2bf(fc1w[i]); }
  for (int i = gt; i < 512 * 128; i += gs) { int k = i >> 7, n = i & 127; fc2T[n * 512 + k] = f2bf(fc2w[i]); }
  for (int i = gt; i < 128 * 32; i += gs) {
    int k = i >> 5, n = i & 31;
    float v = n < 10 ? hwnd[k * 10 + n] : (n < 20 ? wwnd[k * 10 + (n - 10)] : 0.f);
    wcatT[n * 128 + k] = f2bf(v);
  }
}

// ---------------- LN1: x[B,C,H,W] -> ubf[B,H,W,C] bf16 + xcl[B,H,W,C] bf16 ----------------
__global__ __launch_bounds__(256) void ln1_kernel(const float* __restrict__ x,
    const float* __restrict__ g, const float* __restrict__ bt,
    unsigned short* __restrict__ ubf, unsigned short* __restrict__ xcl) {
  int bh = blockIdx.x;
  int b = bh / HH, h = bh % HH;
  __shared__ float lds[WW][CC + 1];
  __shared__ float mu[WW], rs[WW];
  const float* xp = x + ((size_t)b * CC) * HWHW + (size_t)h * WW;
  for (int idx = threadIdx.x; idx < CC * WW; idx += 256) {
    int c = idx / WW, w = idx % WW;
    lds[w][c] = xp[(size_t)c * HWHW + w];
  }
  __syncthreads();
  if (threadIdx.x < WW) {
    int w = threadIdx.x;
    float s = 0.f, ss = 0.f;
    for (int c = 0; c < CC; ++c) { float v = lds[w][c]; s += v; ss += v * v; }
    float m = s * (1.0f / CC);
    float var = ss * (1.0f / CC) - m * m;
    mu[w] = m; rs[w] = rsqrtf(var + 1e-5f);
  }
  __syncthreads();
  unsigned short* up = ubf + (size_t)bh * (WW * CC);
  unsigned short* xc = xcl + (size_t)bh * (WW * CC);
  for (int idx = threadIdx.x; idx < WW * CC; idx += 256) {
    int w = idx >> 7, c = idx & 127;
    float v = lds[w][c];
    up[idx] = f2bf((v - mu[w]) * rs[w] * g[c] + bt[c]);
    xc[idx] = f2bf(v);
  }
}

// ---------------- pd (MFMA): per-token 128->20 projection, scatter to pdh/pdw ----------------
__global__ __launch_bounds__(256) void pd_mfma(const unsigned short* __restrict__ ubf,
    const unsigned short* __restrict__ wcatT, const float* __restrict__ hbnd,
    const float* __restrict__ wbnd, unsigned short* __restrict__ pdh,
    unsigned short* __restrict__ pdw) {
  __shared__ __align__(16) unsigned short sU[64 * 128];
  __shared__ __align__(16) unsigned short sW[32 * 128];
  int tid = threadIdx.x;
  int tok0 = blockIdx.x * 64;
  #pragma unroll
  for (int i = 0; i < 4; ++i) {
    int s = i * 256 + tid; int r = s >> 4, c = s & 15;
    u32x4 v = *reinterpret_cast<const u32x4*>(ubf + (size_t)(tok0 + r) * 128 + c * 8);
    *reinterpret_cast<u32x4*>(sU + r * 128 + ((c ^ (r & 7)) * 8)) = v;
  }
  #pragma unroll
  for (int i = 0; i < 2; ++i) {
    int s = i * 256 + tid; int r = s >> 4, c = s & 15;
    u32x4 v = *reinterpret_cast<const u32x4*>(wcatT + (size_t)r * 128 + c * 8);
    *reinterpret_cast<u32x4*>(sW + r * 128 + ((c ^ (r & 7)) * 8)) = v;
  }
  __syncthreads();
  int wid = tid >> 6, lane = tid & 63, l16 = lane & 15, lk = lane >> 4;
  f32x4 acc[2] = {};
  #pragma unroll
  for (int kk = 0; kk < 4; ++kk) {
    bhalf8 a = ldsFrag<16>(sU, wid * 16 + l16, kk * 4 + lk);
    #pragma unroll
    for (int f = 0; f < 2; ++f) {
      bhalf8 b = ldsFrag<16>(sW, f * 16 + l16, kk * 4 + lk);
      acc[f] = MFMA(a, b, acc[f]);
    }
  }
  #pragma unroll
  for (int f = 0; f < 2; ++f) {
    int n = f * 16 + l16;
    #pragma unroll
    for (int r = 0; r < 4; ++r) {
      int tok = tok0 + wid * 16 + lk * 4 + r;
      float v = acc[f][r];
      if (n < 10) {
        pdh[((size_t)(tok / 56)) * NDP + (size_t)(tok % 56) * 10 + n] = f2bf(v + hbnd[n]);
      } else if (n < 20) {
        int b = tok / HWHW; int rem = tok % HWHW; int hh = rem / 56; int w = rem % 56;
        pdw[((size_t)(b * 56 + w)) * NDP + (size_t)hh * 10 + (n - 10)] = f2bf(v + wbnd[n - 10]);
      }
    }
  }
}

// ---------------- logits GEMM: C[1792,3200] = A[1792,576] @ B^T, bf16 out ----------------
__global__ __launch_bounds__(256) void gemm_logits(
    const unsigned short* __restrict__ A, const unsigned short* __restrict__ BT,
    const float* __restrict__ bias, unsigned short* __restrict__ Cout) {
  __shared__ __align__(16) unsigned short sA[128 * 64];
  __shared__ __align__(16) unsigned short sB[128 * 64];
  int tid = threadIdx.x;
  int row0 = blockIdx.y * 128, col0 = blockIdx.x * 128;
  int wid = tid >> 6, lane = tid & 63;
  int wm = wid >> 1, wn = wid & 1;
  int l16 = lane & 15, lk = lane >> 4;
  f32x4 acc[4][4] = {};
  for (int k0 = 0; k0 < NDP; k0 += 64) {
    #pragma unroll
    for (int i = 0; i < 4; ++i) {
      int s = i * 256 + tid; int r = s >> 3, c = s & 7;
      u32x4 v = *reinterpret_cast<const u32x4*>(A + (size_t)(row0 + r) * NDP + k0 + c * 8);
      *reinterpret_cast<u32x4*>(sA + r * 64 + ((c ^ (r & 7)) * 8)) = v;
    }
    #pragma unroll
    for (int i = 0; i < 4; ++i) {
      int s = i * 256 + tid; int r = s >> 3, c = s & 7;
      u32x4 v = *reinterpret_cast<const u32x4*>(BT + (size_t)(col0 + r) * NDP + k0 + c * 8);
      *reinterpret_cast<u32x4*>(sB + r * 64 + ((c ^ (r & 7)) * 8)) = v;
    }
    __syncthreads();
    bhalf8 af[4][2], bf[4][2];
    #pragma unroll
    for (int f = 0; f < 4; ++f)
      #pragma unroll
      for (int kk = 0; kk < 2; ++kk) {
        af[f][kk] = ldsFrag<8>(sA, wm * 64 + f * 16 + l16, kk * 4 + lk);
        bf[f][kk] = ldsFrag<8>(sB, wn * 64 + f * 16 + l16, kk * 4 + lk);
      }
    #pragma unroll
    for (int i = 0; i < 4; ++i)
      #pragma unroll
      for (int j = 0; j < 4; ++j) {
        acc[i][j] = MFMA(af[i][0], bf[j][0], acc[i][j]);
        acc[i][j] = MFMA(af[i][1], bf[j][1], acc[i][j]);
      }
    __syncthreads();
  }
  #pragma unroll
  for (int i = 0; i < 4; ++i) {
    int rbase = row0 + wm * 64 + i * 16 + lk * 4;
    #pragma unroll
    for (int j = 0; j < 4; ++j) {
      int col = col0 + wn * 64 + j * 16 + l16;
      if (col < HWHW) {
        float bv = bias[col];
        #pragma unroll
        for (int r = 0; r < 4; ++r)
          Cout[(size_t)(rbase + r) * NNP + col] = f2bf(acc[i][j][r] + bv);
      }
    }
  }
}

// ---------------- softmax over contiguous groups of 56 (bf16, row stride 3200) ----------------
__global__ __launch_bounds__(256) void softmax56_kernel(unsigned short* __restrict__ ph,
                                                        unsigned short* __restrict__ pw) {
  int wave = (blockIdx.x * 256 + threadIdx.x) >> 6;
  int lane = threadIdx.x & 63;
  if (wave >= 2 * TOK) return;
  unsigned short* buf = wave < TOK ? ph : pw;
  int row = wave < TOK ? wave : wave - TOK;
  int bh = row / 56, i = row % 56;
  unsigned short* p = buf + (size_t)bh * NNP + (size_t)i * 56;
  float xv = lane < WW ? bf2f(p[lane]) : -INFINITY;
  float m = xv;
  for (int o = 32; o > 0; o >>= 1) m = fmaxf(m, __shfl_xor(m, o));
  float e = lane < WW ? __expf(xv - m) : 0.f;
  float s = e;
  for (int o = 32; o > 0; o >>= 1) s += __shfl_xor(s, o);
  if (lane < WW) p[lane] = f2bf(e / s);
}

// ---------------- mix_h + pc fused: accm = P_h @ U + U @ pc + pc_b  (bf16 out) ----------------
__global__ __launch_bounds__(256) void mixh_pc(const unsigned short* __restrict__ ph,
    const unsigned short* __restrict__ ubf, const unsigned short* __restrict__ pcT,
    const float* __restrict__ pcb, unsigned short* __restrict__ accm) {
  int bh = blockIdx.x;
  int tok0 = bh * 56;
  __shared__ __align__(16) unsigned short sP[64 * 64];
  __shared__ __align__(16) unsigned short sUn[64 * 128];
  __shared__ __align__(16) unsigned short sUt[128 * 64];
  __shared__ __align__(16) unsigned short pcL[128 * 128];
  int tid = threadIdx.x;
  for (int s = tid; s < 512; s += 256) {
    int r = s >> 3, c = s & 7;
    u32x4 v = {0, 0, 0, 0};
    if (r < 56 && c < 7) v = *reinterpret_cast<const u32x4*>(ph + (size_t)bh * NNP + r * 56 + c * 8);
    *reinterpret_cast<u32x4*>(sP + r * 64 + ((c ^ (r & 7)) * 8)) = v;
  }
  for (int s = tid; s < 1024; s += 256) {
    int r = s >> 4, c = s & 15;
    u32x4 v = {0, 0, 0, 0};
    if (r < 56) v = *reinterpret_cast<const u32x4*>(ubf + (size_t)(tok0 + r) * 128 + c * 8);
    *reinterpret_cast<u32x4*>(sUn + r * 128 + ((c ^ (r & 7)) * 8)) = v;
  }
  for (int s = tid; s < 1024; s += 256) {
    int j = s >> 4, cc = s & 15;
    unsigned short e8[8] = {0, 0, 0, 0, 0, 0, 0, 0};
    if (j < 56)
      *reinterpret_cast<u32x4*>(e8) =
          *reinterpret_cast<const u32x4*>(ubf + (size_t)(tok0 + j) * 128 + cc * 8);
    #pragma unroll
    for (int e = 0; e < 8; ++e) {
      int cf = cc * 8 + e;
      sUt[cf * 64 + (((j >> 3) ^ (cf & 7)) * 8) + (j & 7)] = e8[e];
    }
  }
  for (int s = tid; s < 2048; s += 256) {
    int r = s >> 4, c = s & 15;
    u32x4 v = *reinterpret_cast<const u32x4*>(pcT + (size_t)r * 128 + c * 8);
    *reinterpret_cast<u32x4*>(pcL + r * 128 + ((c ^ (r & 7)) * 8)) = v;
  }
  __syncthreads();
  int lane = tid & 63, l16 = lane & 15, lk = lane >> 4, wn = tid >> 6;
  f32x4 acc[4][2] = {};
  #pragma unroll
  for (int kk = 0; kk < 2; ++kk) {
    bhalf8 a[4], b[2];
    #pragma unroll
    for (int i = 0; i < 4; ++i) a[i] = ldsFrag<8>(sP, i * 16 + l16, kk * 4 + lk);
    #pragma unroll
    for (int j = 0; j < 2; ++j) b[j] = ldsFrag<8>(sUt, wn * 32 + j * 16 + l16, kk * 4 + lk);
    #pragma unroll
    for (int i = 0; i < 4; ++i)
      #pragma unroll
      for (int j = 0; j < 2; ++j) acc[i][j] = MFMA(a[i], b[j], acc[i][j]);
  }
  #pragma unroll
  for (int kk = 0; kk < 4; ++kk) {
    bhalf8 a[4], b[2];
    #pragma unroll
    for (int i = 0; i < 4; ++i) a[i] = ldsFrag<16>(sUn, i * 16 + l16, kk * 4 + lk);
    #pragma unroll
    for (int j = 0; j < 2; ++j) b[j] = ldsFrag<16>(pcL, wn * 32 + j * 16 + l16, kk * 4 + lk);
    #pragma unroll
    for (int i = 0; i < 4; ++i)
      #pragma unroll
      for (int j = 0; j < 2; ++j) acc[i][j] = MFMA(a[i], b[j], acc[i][j]);
  }
  #pragma unroll
  for (int i = 0; i < 4; ++i) {
    int tok = i * 16 + lk * 4;
    #pragma unroll
    for (int j = 0; j < 2; ++j) {
      int c = wn * 32 + j * 16 + l16;
      float bv = pcb[c];
      #pragma unroll
      for (int r = 0; r < 4; ++r)
        if (tok + r < 56)
          accm[(size_t)(tok0 + tok + r) * 128 + c] = f2bf(acc[i][j][r] + bv);
    }
  }
}

// ---------------- mix_w + po + residual fused: xt2 = (P_w@U + accm) @ po + po_b + xcl ----------------
__global__ __launch_bounds__(256) void mixw_fin(const unsigned short* __restrict__ pw,
    const unsigned short* __restrict__ ubf, const unsigned short* __restrict__ poT,
    const float* __restrict__ pob, const unsigned short* __restrict__ xcl,
    unsigned short* __restrict__ accXt) {
  int bw = blockIdx.x;
  int bq = bw / 56, w = bw % 56;
  __shared__ __align__(16) unsigned short sP[64 * 64];
  __shared__ __align__(16) unsigned short sUt[128 * 64];
  __shared__ __align__(16) unsigned short sS[64 * 128];
  __shared__ __align__(16) unsigned short poL[128 * 128];
  int tid = threadIdx.x;
  for (int s = tid; s < 512; s += 256) {
    int r = s >> 3, c = s & 7;
    u32x4 v = {0, 0, 0, 0};
    if (r < 56 && c < 7) v = *reinterpret_cast<const u32x4*>(pw + (size_t)bw * NNP + r * 56 + c * 8);
    *reinterpret_cast<u32x4*>(sP + r * 64 + ((c ^ (r & 7)) * 8)) = v;
  }
  for (int s = tid; s < 1024; s += 256) {
    int j = s >> 4, cc = s & 15;
    unsigned short e8[8] = {0, 0, 0, 0, 0, 0, 0, 0};
    if (j < 56)
      *reinterpret_cast<u32x4*>(e8) =
          *reinterpret_cast<const u32x4*>(ubf + ((size_t)bq * HWHW + (size_t)j * 56 + w) * 128 + cc * 8);
    #pragma unroll
    for (int e = 0; e < 8; ++e) {
      int cf = cc * 8 + e;
      sUt[cf * 64 + (((j >> 3) ^ (cf & 7)) * 8) + (j & 7)] = e8[e];
    }
  }
  for (int s = tid; s < 1024; s += 256) {
    int r = s >> 4, c = s & 15;
    u32x4 v = {0, 0, 0, 0};
    if (r < 56) v = *reinterpret_cast<const u32x4*>(accXt + ((size_t)bq * HWHW + (size_t)r * 56 + w) * 128 + c * 8);
    *reinterpret_cast<u32x4*>(sS + r * 128 + ((c ^ (r & 7)) * 8)) = v;
  }
  for (int s = tid; s < 2048; s += 256) {
    int r = s >> 4, c = s & 15;
    u32x4 v = *reinterpret_cast<const u32x4*>(poT + (size_t)r * 128 + c * 8);
    *reinterpret_cast<u32x4*>(poL + r * 128 + ((c ^ (r & 7)) * 8)) = v;
  }
  __syncthreads();
  int lane = tid & 63, l16 = lane & 15, lk = lane >> 4, wn = tid >> 6;
  f32x4 acc1[4][2] = {};
  #pragma unroll
  for (int kk = 0; kk < 2; ++kk) {
    bhalf8 a[4], b[2];
    #pragma unroll
    for (int i = 0; i < 4; ++i) a[i] = ldsFrag<8>(sP, i * 16 + l16, kk * 4 + lk);
    #pragma unroll
    for (int j = 0; j < 2; ++j) b[j] = ldsFrag<8>(sUt, wn * 32 + j * 16 + l16, kk * 4 + lk);
    #pragma unroll
    for (int i = 0; i < 4; ++i)
      #pragma unroll
      for (int j = 0; j < 2; ++j) acc1[i][j] = MFMA(a[i], b[j], acc1[i][j]);
  }
  // sS = accm_tile + yw  (RMW by owner lanes; pad rows stay zero)
  #pragma unroll
  for (int i = 0; i < 4; ++i) {
    #pragma unroll
    for (int j = 0; j < 2; ++j) {
      int col = wn * 32 + j * 16 + l16;
      #pragma unroll
      for (int r = 0; r < 4; ++r) {
        int row = i * 16 + lk * 4 + r;
        int ad = row * 128 + (((col >> 3) ^ (row & 7)) * 8) + (col & 7);
        sS[ad] = f2bf(bf2f(sS[ad]) + acc1[i][j][r]);
      }
    }
  }
  __syncthreads();
  f32x4 acc2[4][2] = {};
  #pragma unroll
  for (int kk = 0; kk < 4; ++kk) {
    bhalf8 a[4], b[2];
    #pragma unroll
    for (int i = 0; i < 4; ++i) a[i] = ldsFrag<16>(sS, i * 16 + l16, kk * 4 + lk);
    #pragma unroll
    for (int j = 0; j < 2; ++j) b[j] = ldsFrag<16>(poL, wn * 32 + j * 16 + l16, kk * 4 + lk);
    #pragma unroll
    for (int i = 0; i < 4; ++i)
      #pragma unroll
      for (int j = 0; j < 2; ++j) acc2[i][j] = MFMA(a[i], b[j], acc2[i][j]);
  }
  #pragma unroll
  for (int i = 0; i < 4; ++i) {
    #pragma unroll
    for (int j = 0; j < 2; ++j) {
      int c = wn * 32 + j * 16 + l16;
      float bv = pob[c];
      #pragma unroll
      for (int r = 0; r < 4; ++r) {
        int row = i * 16 + lk * 4 + r;
        if (row < 56) {
          size_t t = (size_t)bq * HWHW + (size_t)row * 56 + w;
          float z = acc2[i][j][r] + bv + bf2f(xcl[t * 128 + c]);
          accXt[t * 128 + c] = f2bf(z);
        }
      }
    }
  }
}

// ---------------- fused LN2+MLP: out = T(xt2 + gelu(LN(xt2)@fc1+b1)@fc2+b2) ----------------
__global__ __launch_bounds__(256) void mlp2(const unsigned short* __restrict__ xt2,
    const unsigned short* __restrict__ w1T, const float* __restrict__ b1,
    const unsigned short* __restrict__ w2T, const float* __restrict__ b2,
    const float* __restrict__ g, const float* __restrict__ bt,
    float* __restrict__ out) {
  __shared__ __align__(16) char smem[65536];
  unsigned short* sV = (unsigned short*)smem;                 // 16K: 64x128 bf16
  unsigned short* sW = (unsigned short*)(smem + 16384);       // 32K: 128x128 bf16
  unsigned short* sH = (unsigned short*)(smem + 49152);       // 16K: 64x128 bf16
  float* T = (float*)(smem + 16384);                          // 64x129 fp32 (overlaps sW+sH)
  __shared__ float b1s[512];
  __shared__ float gls[128], bls[128], b2s[128];
  __shared__ float psum[64][4], psq[64][4];
  __shared__ float mus[64], rss[64];
  int tid = threadIdx.x;
  int tok0 = blockIdx.x * 64;
  if (tid < 128) { gls[tid] = g[tid]; bls[tid] = bt[tid]; b2s[tid] = b2[tid]; }
  for (int i = tid; i < 512; i += 256) b1s[i] = b1[i];
  for (int s = tid; s < 1024; s += 256) {
    int r = s >> 4, c = s & 15;
    u32x4 v = *reinterpret_cast<const u32x4*>(xt2 + (size_t)(tok0 + r) * 128 + c * 8);
    #pragma unroll
    for (int e = 0; e < 4; ++e) {
      T[r * 129 + c * 8 + 2 * e]     = bf2f((unsigned short)(v[e] & 0xFFFFu));
      T[r * 129 + c * 8 + 2 * e + 1] = bf2f((unsigned short)(v[e] >> 16));
    }
  }
  __syncthreads();
  {
    int t = tid & 63, q = tid >> 6;
    float s1 = 0.f, s2 = 0.f;
    #pragma unroll 8
    for (int i = 0; i < 32; ++i) { float v = T[t * 129 + q * 32 + i]; s1 += v; s2 += v * v; }
    psum[t][q] = s1; psq[t][q] = s2;
  }
  __syncthreads();
  if (tid < 64) {
    float s1 = psum[tid][0] + psum[tid][1] + psum[tid][2] + psum[tid][3];
    float s2 = psq[tid][0] + psq[tid][1] + psq[tid][2] + psq[tid][3];
    float m = s1 * (1.0f / CC);
    float var = s2 * (1.0f / CC) - m * m;
    mus[tid] = m; rss[tid] = rsqrtf(var + 1e-5f);
  }
  __syncthreads();
  for (int s = tid; s < 1024; s += 256) {
    int r = s >> 4, c = s & 15;
    float m = mus[r], rv = rss[r];
    unsigned int wds[4];
    #pragma unroll
    for (int e = 0; e < 4; ++e) {
      int c0 = c * 8 + 2 * e;
      float v0 = (T[r * 129 + c0]     - m) * rv * gls[c0]     + bls[c0];
      float v1 = (T[r * 129 + c0 + 1] - m) * rv * gls[c0 + 1] + bls[c0 + 1];
      wds[e] = pack2(v0, v1);
    }
    u32x4 v = {wds[0], wds[1], wds[2], wds[3]};
    *reinterpret_cast<u32x4*>(sV + r * 128 + ((c ^ (r & 7)) * 8)) = v;
  }
  __syncthreads();
  int lane = tid & 63, l16 = lane & 15, lk = lane >> 4, wid = tid >> 6;
  int wmA = wid >> 1, wnA = wid & 1;   // fc1: tok-half / hid-half
  int wc = wid >> 1, wt = wid & 1;     // fc2: c-half / tok-half
  f32x4 acc2[4][2] = {};
  for (int hc = 0; hc < 4; ++hc) {
    for (int s = tid; s < 2048; s += 256) {
      int r = s >> 4, c = s & 15;
      u32x4 v = *reinterpret_cast<const u32x4*>(w1T + (size_t)(hc * 128 + r) * 128 + c * 8);
      *reinterpret_cast<u32x4*>(sW + r * 128 + ((c ^ (r & 7)) * 8)) = v;
    }
    __syncthreads();
    f32x4 acc1[2][4] = {};
    #pragma unroll
    for (int kk = 0; kk < 4; ++kk) {
      bhalf8 a[2], b[4];
      #pragma unroll
      for (int i = 0; i < 2; ++i) a[i] = ldsFrag<16>(sV, wmA * 32 + i * 16 + l16, kk * 4 + lk);
      #pragma unroll
      for (int j = 0; j < 4; ++j) b[j] = ldsFrag<16>(sW, wnA * 64 + j * 16 + l16, kk * 4 + lk);
      #pragma unroll
      for (int i = 0; i < 2; ++i)
        #pragma unroll
        for (int j = 0; j < 4; ++j) acc1[i][j] = MFMA(a[i], b[j], acc1[i][j]);
    }
    #pragma unroll
    for (int i = 0; i < 2; ++i) {
      #pragma unroll
      for (int j = 0; j < 4; ++j) {
        int hid = wnA * 64 + j * 16 + l16;
        float bv = b1s[hc * 128 + hid];
        #pragma unroll
        for (int r = 0; r < 4; ++r) {
          int tok = wmA * 32 + i * 16 + lk * 4 + r;
          float hval = gelu_f(acc1[i][j][r] + bv);
          sH[tok * 128 + (((hid >> 3) ^ (tok & 7)) * 8) + (hid & 7)] = f2bf(hval);
        }
      }
    }
    __syncthreads();
    for (int s = tid; s < 2048; s += 256) {
      int r = s >> 4, c = s & 15;
      u32x4 v = *reinterpret_cast<const u32x4*>(w2T + (size_t)r * 512 + hc * 128 + c * 8);
      *reinterpret_cast<u32x4*>(sW + r * 128 + ((c ^ (r & 7)) * 8)) = v;
    }
    __syncthreads();
    #pragma unroll
    for (int kk = 0; kk < 4; ++kk) {
      bhalf8 a[4], b[2];
      #pragma unroll
      for (int i = 0; i < 4; ++i) a[i] = ldsFrag<16>(sW, wc * 64 + i * 16 + l16, kk * 4 + lk);
      #pragma unroll
      for (int j = 0; j < 2; ++j) b[j] = ldsFrag<16>(sH, wt * 32 + j * 16 + l16, kk * 4 + lk);
      #pragma unroll
      for (int i = 0; i < 4; ++i)
        #pragma unroll
        for (int j = 0; j < 2; ++j) acc2[i][j] = MFMA(a[i], b[j], acc2[i][j]);
    }
    __syncthreads();
  }
  // epilogue: acc2 -> T[tok][c], add residual+b2, transposed store
  #pragma unroll
  for (int i = 0; i < 4; ++i) {
    #pragma unroll
    for (int j = 0; j < 2; ++j) {
      int tok = wt * 32 + j * 16 + l16;
      #pragma unroll
      for (int r = 0; r < 4; ++r) {
        int c = wc * 64 + i * 16 + lk * 4 + r;
        T[tok * 129 + c] = acc2[i][j][r];
      }
    }
  }
  __syncthreads();
  for (int s = tid; s < 1024; s += 256) {
    int r = s >> 4, c = s & 15;
    u32x4 v = *reinterpret_cast<const u32x4*>(xt2 + (size_t)(tok0 + r) * 128 + c * 8);
    #pragma unroll
    for (int e = 0; e < 4; ++e) {
      int c0 = c * 8 + 2 * e;
      T[r * 129 + c0]     += bf2f((unsigned short)(v[e] & 0xFFFFu)) + b2s[c0];
      T[r * 129 + c0 + 1] += bf2f((unsigned short)(v[e] >> 16))     + b2s[c0 + 1];
    }
  }
  __syncthreads();
  int bq = tok0 / HWHW;
  int pos0 = tok0 % HWHW;
  for (int s = tid; s < 8192; s += 256) {
    int c = s >> 6, t = s & 63;
    out[((size_t)(bq * CC + c)) * HWHW + pos0 + t] = T[t * 129 + c];
  }
}

extern "C" void kernel_launch(void* const* d_in, const int* in_sizes, int n_in,
                              void* d_out, int out_size, void* d_ws, size_t ws_size,
                              hipStream_t stream) {
  const float* x     = (const float*)d_in[0];
  const float* ln1_g = (const float*)d_in[1];
  const float* ln1_b = (const float*)d_in[2];
  const float* h_wnd = (const float*)d_in[3];
  const float* h_bnd = (const float*)d_in[4];
  const float* h_wnn = (const float*)d_in[5];
  const float* h_bnn = (const float*)d_in[6];
  const float* w_wnd = (const float*)d_in[7];
  const float* w_bnd = (const float*)d_in[8];
  const float* w_wnn = (const float*)d_in[9];
  const float* w_bnn = (const float*)d_in[10];
  const float* pc_w  = (const float*)d_in[11];
  const float* pc_b  = (const float*)d_in[12];
  const float* po_w  = (const float*)d_in[13];
  const float* po_b  = (const float*)d_in[14];
  const float* ln2_g = (const float*)d_in[15];
  const float* ln2_b = (const float*)d_in[16];
  const float* fc1_w = (const float*)d_in[17];
  const float* fc1_b = (const float*)d_in[18];
  const float* fc2_w = (const float*)d_in[19];
  const float* fc2_b = (const float*)d_in[20];
  float* out = (float*)d_out;
  char* ws = (char*)d_ws;

  // ---- workspace layout (bytes), total 111,845,376 ----
  unsigned short* ubf   = (unsigned short*)(ws + 0);            // 25,690,112
  unsigned short* xcl   = (unsigned short*)(ws + 25690112);     // 25,690,112
  unsigned short* accXt = (unsigned short*)(ws + 51380224);     // 25,690,112 (accm then xt2 in-place)
  unsigned short* pdh   = (unsigned short*)(ws + 77070336);     //  2,064,384
  unsigned short* pdw   = (unsigned short*)(ws + 79134720);     //  2,064,384
  unsigned short* ph    = (unsigned short*)(ws + 81199104);     // 11,468,800
  unsigned short* pw    = (unsigned short*)(ws + 92667904);     // 11,468,800
  unsigned short* wnnTh = (unsigned short*)(ws + 104136704);    //  3,686,400
  unsigned short* wnnTw = (unsigned short*)(ws + 107823104);    //  3,686,400
  unsigned short* pcT   = (unsigned short*)(ws + 111509504);    //     32,768
  unsigned short* poT   = (unsigned short*)(ws + 111542272);    //     32,768
  unsigned short* fc1T  = (unsigned short*)(ws + 111575040);    //    131,072
  unsigned short* fc2T  = (unsigned short*)(ws + 111706112);    //    131,072
  unsigned short* wcatT = (unsigned short*)(ws + 111837184);    //      8,192

  wcvt_kernel<<<2048, 256, 0, stream>>>(h_wnn, w_wnn, pc_w, po_w, fc1_w, fc2_w,
      h_wnd, w_wnd, wnnTh, wnnTw, pcT, poT, fc1T, fc2T, wcatT, (u32x4*)pdh);
  ln1_kernel<<<BH, 256, 0, stream>>>(x, ln1_g, ln1_b, ubf, xcl);
  pd_mfma<<<TOK / 64, 256, 0, stream>>>(ubf, wcatT, h_bnd, w_bnd, pdh, pdw);
  gemm_logits<<<dim3(NNP / 128, BH / 128), 256, 0, stream>>>(pdh, wnnTh, h_bnn, ph);
  gemm_logits<<<dim3(NNP / 128, BH / 128), 256, 0, stream>>>(pdw, wnnTw, w_bnn, pw);
  softmax56_kernel<<<(2 * TOK) / 4, 256, 0, stream>>>(ph, pw);
  mixh_pc<<<BH, 256, 0, stream>>>(ph, ubf, pcT, pc_b, accXt);
  mixw_fin<<<BB * WW, 256, 0, stream>>>(pw, ubf, poT, po_b, xcl, accXt);
  mlp2<<<TOK / 64, 256, 0, stream>>>(accXt, fc1T, fc1_b, fc2T, fc2_b, ln2_g, ln2_b, out);
}